// Round 4
// 151.760 us; speedup vs baseline: 1.0459x; 1.0459x over previous
//
#include <hip/hip_runtime.h>
#include <hip/hip_fp16.h>
#include <math.h>

typedef _Float16 f16;
typedef _Float16 f16x8 __attribute__((ext_vector_type(8)));
typedef float f32x4 __attribute__((ext_vector_type(4)));
typedef float f32x16 __attribute__((ext_vector_type(16)));
typedef unsigned int u32;
typedef unsigned int u32x4 __attribute__((ext_vector_type(4)));

#define BB 8
#define SS 2048
#define DD 256
#define HH 4
#define DHH 64

#define LOG2E 1.44269504088896340736f
#define MOFF2 (4.0f * LOG2E)          // softmax offset (log2 domain)
#define QSCALE (0.125f * LOG2E)       // 1/sqrt(DH) * log2e, folded into Q store

static __device__ __forceinline__ u32 pkrtz(float a, float b) {
  auto t = __builtin_amdgcn_cvt_pkrtz(a, b);  // __fp16 ext_vector_type(2)
  return __builtin_bit_cast(u32, t);
}

// ---------------------------------------------------------------------------
// Kernel 1: weight pack via LDS transpose tiles (coalesced read AND write).
// ---------------------------------------------------------------------------
__global__ __launch_bounds__(256) void prep_kernel(
    const float* __restrict__ wq, const float* __restrict__ wk,
    const float* __restrict__ wv, const float* __restrict__ wo,
    f16* __restrict__ wqkvT, f16* __restrict__ woT) {
  __shared__ f16 lds[64][72];  // [k_local][dout_local], +8 pad
  int dout0 = blockIdx.x * 64;   // 0..1023
  int k0 = blockIdx.y * 64;      // 0..255
  const float* src;
  f16* dst;
  int col0, drow;
  if (dout0 < 256)      { src = wq; dst = wqkvT; col0 = dout0;       drow = dout0; }
  else if (dout0 < 512) { src = wk; dst = wqkvT; col0 = dout0 - 256; drow = dout0; }
  else if (dout0 < 768) { src = wv; dst = wqkvT; col0 = dout0 - 512; drow = dout0; }
  else                  { src = wo; dst = woT;   col0 = dout0 - 768; drow = dout0 - 768; }

  int dl = threadIdx.x & 63, kl = threadIdx.x >> 6;
#pragma unroll
  for (int i = 0; i < 16; i++) {
    int kloc = i * 4 + kl;
    lds[kloc][dl] = (f16)src[(size_t)(k0 + kloc) * 256 + col0 + dl];
  }
  __syncthreads();
  int row_l = threadIdx.x >> 2, kq = threadIdx.x & 3;
  f16x8 v0, v1;
#pragma unroll
  for (int j = 0; j < 8; j++) v0[j] = lds[kq * 16 + j][row_l];
#pragma unroll
  for (int j = 0; j < 8; j++) v1[j] = lds[kq * 16 + 8 + j][row_l];
  f16* p = dst + (size_t)(drow + row_l) * 256 + k0 + kq * 16;
  *(f16x8*)p = v0;
  *(f16x8*)(p + 8) = v1;
}

// ---------------------------------------------------------------------------
// Kernel 2: fused QKV GEMM. Grid (256,3). A VGPR-resident; B LDS-staged
// fragment-major with register prefetch. V via LDS transpose -> V^T rows.
// Q is stored pre-scaled by log2e/8 (single f16 rounding; folds the softmax
// scale + log2-domain conversion out of the attention inner loop).
// ---------------------------------------------------------------------------
__global__ __launch_bounds__(256) void qkv_gemm(
    const float* __restrict__ x, const f16* __restrict__ wT,
    f16* __restrict__ Q, f16* __restrict__ K, f16* __restrict__ VT) {
  __shared__ __attribute__((aligned(16))) f16 bstage[8][4][64][8];  // 32 KB
  __shared__ __attribute__((aligned(16))) f16 lds_t[64][72];        // 9.2 KB
  int m0 = blockIdx.x * 64;
  int which = blockIdx.y;        // 0=Q, 1=K, 2=V
  int nbase = which * 256;
  int wave = threadIdx.x >> 6, lane = threadIdx.x & 63;
  int lm = lane & 15, quad = lane >> 4;
  float qsc = (which == 0) ? QSCALE : 1.0f;

  const float* arow = x + (size_t)(m0 + wave * 16 + lm) * 256 + quad * 8;
  f16x8 a[8];
#pragma unroll
  for (int kk = 0; kk < 8; kk++) {
    f32x4 a0 = *(const f32x4*)(arow + kk * 32);
    f32x4 a1 = *(const f32x4*)(arow + kk * 32 + 4);
#pragma unroll
    for (int j = 0; j < 4; j++) { a[kk][j] = (f16)a0[j]; a[kk][j + 4] = (f16)a1[j]; }
  }

  f16x8 breg[8];
  auto bload = [&](int n0) {
#pragma unroll
    for (int kk = 0; kk < 8; kk++)
      breg[kk] = *(const f16x8*)(wT + (size_t)(n0 + wave * 16 + lm) * 256 + kk * 32 + quad * 8);
  };
  bload(nbase);

  int bb = m0 >> 11, s0 = m0 & 2047;
  for (int i = 0; i < 4; i++) {
    int n0 = nbase + i * 64;
#pragma unroll
    for (int kk = 0; kk < 8; kk++)
      *(f16x8*)&bstage[kk][wave][lane][0] = breg[kk];
    __syncthreads();
    if (i + 1 < 4) bload(nbase + (i + 1) * 64);

    f32x4 acc[4] = {};
#pragma unroll
    for (int kk = 0; kk < 8; kk++)
#pragma unroll
      for (int nt = 0; nt < 4; nt++) {
        f16x8 b = *(const f16x8*)&bstage[kk][nt][lane][0];
        acc[nt] = __builtin_amdgcn_mfma_f32_16x16x32_f16(a[kk], b, acc[nt], 0, 0, 0);
      }

    if (which < 2) {
      f16* dst = (which == 0) ? Q : K;
      int nb = n0 & 255;
#pragma unroll
      for (int nt = 0; nt < 4; nt++) {
        int dout = nb + nt * 16 + lm;
        int h = dout >> 6, dh = dout & 63;
#pragma unroll
        for (int r = 0; r < 4; r++) {
          int s = s0 + wave * 16 + quad * 4 + r;
          dst[(((size_t)(bb * HH + h) * SS + s) << 6) + dh] = (f16)(acc[nt][r] * qsc);
        }
      }
    } else {
      int h = i;
#pragma unroll
      for (int nt = 0; nt < 4; nt++)
#pragma unroll
        for (int r = 0; r < 4; r++)
          lds_t[nt * 16 + lm][wave * 16 + quad * 4 + r] = (f16)acc[nt][r];
      __syncthreads();
      int rr = threadIdx.x >> 2, cc = threadIdx.x & 3;
      f16* vrow = VT + ((size_t)(bb * HH + h) * DHH + rr) * SS + s0;
      f16x8 v0 = *(const f16x8*)&lds_t[rr][cc * 16];
      f16x8 v1 = *(const f16x8*)&lds_t[rr][cc * 16 + 8];
      *(f16x8*)(vrow + cc * 16) = v0;
      *(f16x8*)(vrow + cc * 16 + 8) = v1;
    }
    __syncthreads();
  }
}

// ---------------------------------------------------------------------------
// Kernel 3: flash attention, 32x32x16 MFMA core. Grid (16,4,8), block = 256
// threads / 4 waves; each wave owns 32 q-rows. Swapped QK^T (S^T = K Q^T) so
// each lane holds a full P-row slice in registers: softmax is pure VALU
// (exp2 only -- scale AND offset pre-folded), P->A-frag repack is
// cvt_pkrtz + __builtin_amdgcn_permlane32_swap (NO lds_p round trip; builtin
// not inline asm -- gfx950 has a VALU-write->permlane-swap wait-state hazard
// that raw asm does not mitigate: rounds 2/3 failed from stale reads).
// K/V LDS fragment-major (conflict-free b128), double-buffered, one
// barrier/tile, 2-ahead register prefetch. l-row-sums ride the MFMA pipe
// (ones-trick); accL/accO row maps identical by construction.
// Plain loads + ds_write only (async global_load_lds BANNED: rounds 3/4).
// ---------------------------------------------------------------------------
__global__ __launch_bounds__(256, 2) void attn_kernel(
    const f16* __restrict__ Q, const f16* __restrict__ K,
    const f16* __restrict__ VT, f16* __restrict__ ctx) {
  __shared__ __attribute__((aligned(16))) f16 kbuf[2][8][64][8];  // 16 KB
  __shared__ __attribute__((aligned(16))) f16 vbuf[2][8][64][8];  // 16 KB

  int qb = blockIdx.x, hd = blockIdx.y, b = blockIdx.z;
  int w = threadIdx.x >> 6, lane = threadIdx.x & 63;
  int l31 = lane & 31, hi = lane >> 5, hi8 = hi * 8;
  const f16* Qbh = Q + (size_t)(b * HH + hd) * SS * DHH;
  const f16* Kbh = K + (size_t)(b * HH + hd) * SS * DHH;
  const f16* Vbh = VT + (size_t)(b * HH + hd) * DHH * SS;
  int q0 = qb * 128 + w * 32;

  // wave w stages K-frags {nt,kp=w} and V-frags {nt2,kp2=w}  (frag = nt*4+kp)
  f16x8 tk0, tk1, tv0, tv1;
  auto stage_load = [&](int key0) {
    tk0 = *(const f16x8*)(Kbh + (size_t)(key0 + l31) * DHH + w * 16 + hi8);
    tk1 = *(const f16x8*)(Kbh + (size_t)(key0 + 32 + l31) * DHH + w * 16 + hi8);
    tv0 = *(const f16x8*)(Vbh + (size_t)l31 * SS + key0 + w * 16 + hi8);
    tv1 = *(const f16x8*)(Vbh + (size_t)(32 + l31) * SS + key0 + w * 16 + hi8);
  };
  auto stage_write = [&](int buf) {
    *(f16x8*)&kbuf[buf][w][lane][0] = tk0;
    *(f16x8*)&kbuf[buf][4 + w][lane][0] = tk1;
    *(f16x8*)&vbuf[buf][w][lane][0] = tv0;
    *(f16x8*)&vbuf[buf][4 + w][lane][0] = tv1;
  };

  // Q fragments resident (already scaled by log2e/8 at projection)
  f16x8 aq[4];
  {
    const f16* qrow = Qbh + (size_t)(q0 + l31) * DHH + hi8;
#pragma unroll
    for (int kp = 0; kp < 4; kp++) aq[kp] = *(const f16x8*)(qrow + kp * 16);
  }
  f16x8 vones;
#pragma unroll
  for (int j = 0; j < 8; j++) vones[j] = (f16)1.0f;
  f32x16 minit;  // C-operand preload: S^T starts at -4*log2e (softmax offset)
#pragma unroll
  for (int r = 0; r < 16; r++) minit[r] = -MOFF2;

  f32x16 accO0, accO1, accL;
#pragma unroll
  for (int r = 0; r < 16; r++) { accO0[r] = 0.f; accO1[r] = 0.f; accL[r] = 0.f; }

  // prologue: tile 0 -> buf 0; prefetch tile 1 into regs
  stage_load(0);
  stage_write(0);
  stage_load(64);

  const int NT = SS / 64;  // 32 tiles
  for (int t = 0; t < NT; t++) {
    int cur = t & 1;
    __syncthreads();  // buf[cur] visible; prior reads of buf[1-cur] done

    if (t + 1 < NT) {
      stage_write(cur ^ 1);                       // write prefetched tile t+1
      if (t + 2 < NT) stage_load((t + 2) * 64);   // lands during compute
    }

    // ---- S^T = K (Q*log2e/8)^T - 4*log2e : col=q (lane-local P rows) ----
    f32x16 accST[2];
#pragma unroll
    for (int kp = 0; kp < 4; kp++)
#pragma unroll
      for (int nt = 0; nt < 2; nt++) {
        f16x8 kf = *(const f16x8*)&kbuf[cur][nt * 4 + kp][lane][0];
        accST[nt] = __builtin_amdgcn_mfma_f32_32x32x16_f16(
            kf, aq[kp], kp == 0 ? minit : accST[nt], 0, 0, 0);
      }

    // ---- P = exp2(S^T) in-register; repack into PV A-fragments ----
    // lane holds key_local = 8*bq + 4*hi + i  (u[bq][wd] = pk of i=2wd,2wd+1).
    // HK recipe (T12, refcheck'd): r = swap(lowkey_word, highkey_word);
    // r[0] = frag word for the low k-slot, r[1] = word for the +4 slot.
    f16x8 pa[4];
#pragma unroll
    for (int nt = 0; nt < 2; nt++) {
      u32 u[4][2];
#pragma unroll
      for (int bq = 0; bq < 4; bq++) {
        float p0 = __builtin_amdgcn_exp2f(accST[nt][4 * bq + 0]);
        float p1 = __builtin_amdgcn_exp2f(accST[nt][4 * bq + 1]);
        float p2 = __builtin_amdgcn_exp2f(accST[nt][4 * bq + 2]);
        float p3 = __builtin_amdgcn_exp2f(accST[nt][4 * bq + 3]);
        u[bq][0] = pkrtz(p0, p1);
        u[bq][1] = pkrtz(p2, p3);
      }
#pragma unroll
      for (int sl = 0; sl < 2; sl++) {
        auto r0 = __builtin_amdgcn_permlane32_swap(u[2 * sl][0], u[2 * sl + 1][0],
                                                   false, false);
        auto r1 = __builtin_amdgcn_permlane32_swap(u[2 * sl][1], u[2 * sl + 1][1],
                                                   false, false);
        u32x4 wv = {(u32)r0[0], (u32)r1[0], (u32)r0[1], (u32)r1[1]};
        pa[nt * 2 + sl] = __builtin_bit_cast(f16x8, wv);
      }
    }

    // ---- O += P V ; l += P @ ones (row maps of accL and accO identical) ----
#pragma unroll
    for (int ks = 0; ks < 4; ks++) {
      accL = __builtin_amdgcn_mfma_f32_32x32x16_f16(pa[ks], vones, accL, 0, 0, 0);
      f16x8 v0 = *(const f16x8*)&vbuf[cur][ks][lane][0];
      accO0 = __builtin_amdgcn_mfma_f32_32x32x16_f16(pa[ks], v0, accO0, 0, 0, 0);
      f16x8 v1 = *(const f16x8*)&vbuf[cur][4 + ks][lane][0];
      accO1 = __builtin_amdgcn_mfma_f32_32x32x16_f16(pa[ks], v1, accO1, 0, 0, 0);
    }
  }

  // ---- epilogue: ctx[b,s, hd*64+dh] fp16 ----
#pragma unroll
  for (int r = 0; r < 16; r++) {
    float rinv = __builtin_amdgcn_rcpf(accL[r]);
    int s = q0 + (r & 3) + 8 * (r >> 2) + 4 * hi;
    f16* dst = ctx + (size_t)(b * SS + s) * DD + hd * DHH + l31;
    dst[0]  = (f16)(accO0[r] * rinv);
    dst[32] = (f16)(accO1[r] * rinv);
  }
}

// ---------------------------------------------------------------------------
// Kernel 4: out = ctx @ W_o + b_o (fp32). Grid (256,2). A VGPR-resident,
// B LDS-staged with register prefetch.
// ---------------------------------------------------------------------------
__global__ __launch_bounds__(256) void out_gemm(
    const f16* __restrict__ ctxh, const f16* __restrict__ woT,
    const float* __restrict__ bo, float* __restrict__ out) {
  __shared__ __attribute__((aligned(16))) f16 bstage[8][4][64][8];  // 32 KB
  int m0 = blockIdx.x * 64;
  int nbase = blockIdx.y * 128;
  int wave = threadIdx.x >> 6, lane = threadIdx.x & 63;
  int lm = lane & 15, quad = lane >> 4;
  const f16* arow = ctxh + (size_t)(m0 + wave * 16 + lm) * 256 + quad * 8;
  f16x8 a[8];
#pragma unroll
  for (int kk = 0; kk < 8; kk++) a[kk] = *(const f16x8*)(arow + kk * 32);

  f16x8 breg[8];
  auto bload = [&](int n0) {
#pragma unroll
    for (int kk = 0; kk < 8; kk++)
      breg[kk] = *(const f16x8*)(woT + (size_t)(n0 + wave * 16 + lm) * 256 + kk * 32 + quad * 8);
  };
  bload(nbase);

  for (int i = 0; i < 2; i++) {
    int n0 = nbase + i * 64;
#pragma unroll
    for (int kk = 0; kk < 8; kk++)
      *(f16x8*)&bstage[kk][wave][lane][0] = breg[kk];
    __syncthreads();
    if (i + 1 < 2) bload(nbase + 64);

    f32x4 acc[4] = {};
#pragma unroll
    for (int kk = 0; kk < 8; kk++)
#pragma unroll
      for (int nt = 0; nt < 4; nt++) {
        f16x8 bfr = *(const f16x8*)&bstage[kk][nt][lane][0];
        acc[nt] = __builtin_amdgcn_mfma_f32_16x16x32_f16(a[kk], bfr, acc[nt], 0, 0, 0);
      }
#pragma unroll
    for (int nt = 0; nt < 4; nt++) {
      int dout = n0 + nt * 16 + lm;
      float bias = bo[dout];
#pragma unroll
      for (int r = 0; r < 4; r++) {
        int t = m0 + wave * 16 + quad * 4 + r;
        out[(size_t)t * 256 + dout] = acc[nt][r] + bias;
      }
    }
    __syncthreads();
  }
}

// ---------------------------------------------------------------------------
extern "C" void kernel_launch(void* const* d_in, const int* in_sizes, int n_in,
                              void* d_out, int out_size, void* d_ws, size_t ws_size,
                              hipStream_t stream) {
  const float* x  = (const float*)d_in[0];
  const float* wq = (const float*)d_in[1];
  const float* wk = (const float*)d_in[2];
  const float* wv = (const float*)d_in[3];
  const float* wo = (const float*)d_in[4];
  const float* bo = (const float*)d_in[5];
  float* out = (float*)d_out;

  char* ws = (char*)d_ws;
  const size_t SZ = 8388608;  // 16384*256*2 bytes
  f16* Qb    = (f16*)(ws);
  f16* Kb    = (f16*)(ws + SZ);
  f16* VTb   = (f16*)(ws + 2 * SZ);
  f16* ctxh  = (f16*)(ws + 3 * SZ);
  f16* wqkvT = (f16*)(ws + 4 * SZ);            // 768*256*2 = 393216
  f16* woT   = (f16*)(ws + 4 * SZ + 393216);   // 256*256*2 = 131072

  hipLaunchKernelGGL(prep_kernel, dim3(16, 4), dim3(256), 0, stream,
                     wq, wk, wv, wo, wqkvT, woT);
  hipLaunchKernelGGL(qkv_gemm, dim3(256, 3), dim3(256), 0, stream,
                     x, wqkvT, Qb, Kb, VTb);
  hipLaunchKernelGGL(attn_kernel, dim3(16, 4, 8), dim3(256), 0, stream,
                     Qb, Kb, VTb, ctxh);
  hipLaunchKernelGGL(out_gemm, dim3(256, 2), dim3(256), 0, stream,
                     ctxh, woT, bo, out);
}